// Round 6
// baseline (200.801 us; speedup 1.0000x reference)
//
#include <hip/hip_runtime.h>
#include <hip/hip_bf16.h>

typedef __attribute__((ext_vector_type(8))) short short8;
typedef __attribute__((ext_vector_type(4))) float f32x4;

#define NPROTO 64
#define DIM    512
#define TAU_INV 5.0f

__device__ __forceinline__ unsigned short f2bf(float f) {
    union { float f; unsigned int u; } v; v.f = f;
    unsigned int r = v.u + 0x7FFFu + ((v.u >> 16) & 1u);  // round-to-nearest-even
    return (unsigned short)(r >> 16);
}

// ---------------------------------------------------------------------------
// Prep: p_norm (normalized protos, bf16, [64][512]) and protos^T (raw, bf16,
// [512][64]).
// ---------------------------------------------------------------------------
__global__ void pb_prep(const float* __restrict__ protos,
                        unsigned short* __restrict__ pnorm,
                        unsigned short* __restrict__ protosT) {
    const int k    = blockIdx.x;
    const int lane = threadIdx.x;
    const float* row = protos + k * DIM;
    float x[8];
    float ss = 0.0f;
#pragma unroll
    for (int j = 0; j < 8; ++j) {
        x[j] = row[lane * 8 + j];
        ss += x[j] * x[j];
    }
#pragma unroll
    for (int m = 1; m < 64; m <<= 1) ss += __shfl_xor(ss, m, 64);
    const float s = 1.0f / fmaxf(sqrtf(ss), 1e-12f);
    short8 pn;
#pragma unroll
    for (int j = 0; j < 8; ++j) pn[j] = (short)f2bf(x[j] * s);
    *reinterpret_cast<short8*>(pnorm + k * DIM + lane * 8) = pn;
#pragma unroll
    for (int j = 0; j < 8; ++j)
        protosT[(lane * 8 + j) * NPROTO + k] = f2bf(x[j]);
}

// ---------------------------------------------------------------------------
// Main v6: CONTIGUOUS global reads. Each wave stages its 16 rows through a
// wave-private 8KB LDS tile (K split in 2 halves of 256 cols): every global
// load instr is a contiguous 1KB half-row (lane i -> cols i*4..i*4+3).
// f32->bf16 convert + XOR-swizzled LDS write; MFMA A-fragments read back
// bank-conflict-free. |z|^2 computed from f32 during staging (4-stage
// butterfly per row + one deferred cross-group reduce). No barriers.
// Everything else identical to v2 (167us baseline).
// ---------------------------------------------------------------------------
__global__ __launch_bounds__(256, 4) void pb_main(
    const float* __restrict__ seg,
    const unsigned short* __restrict__ pnorm,    // [64][512] bf16
    const unsigned short* __restrict__ protosT,  // [512][64] bf16
    float* __restrict__ out_pat,                 // [N][512]
    float* __restrict__ out_w,                   // [N][64]
    float* __restrict__ out_log) {               // [N][64]

    __shared__ unsigned short lds_all[4 * 16 * 256];  // 32KB, 8KB per wave

    const int wid  = (int)(threadIdx.x >> 6);
    const int lane = (int)(threadIdx.x & 63);
    const int g    = lane >> 4;
    const int r16  = lane & 15;
    const long n0  = ((long)blockIdx.x * 4 + wid) * 16;  // wave's 16 rows

    char* wlds = reinterpret_cast<char*>(lds_all + wid * 16 * 256);  // 8KB

    f32x4 acc[4] = {};
    float ss_own = 0.0f;                 // per-g partial of own row's |z|^2
    const int wr_slot = (lane >> 1) & 31;

    for (int h = 0; h < 2; ++h) {
        // ---- stage 16 half-rows (each instr = 1KB contiguous) -------------
        const float* sp = seg + n0 * DIM + h * 256 + lane * 4;
        f32x4 v[4];
#pragma unroll
        for (int i = 0; i < 4; ++i)
            v[i] = *reinterpret_cast<const f32x4*>(sp + i * DIM);
#pragma unroll
        for (int ch = 0; ch < 4; ++ch) {
            f32x4 nv[4];
            if (ch < 3) {
#pragma unroll
                for (int i = 0; i < 4; ++i)
                    nv[i] = *reinterpret_cast<const f32x4*>(sp + ((ch + 1) * 4 + i) * DIM);
            }
#pragma unroll
            for (int i = 0; i < 4; ++i) {
                const int row = ch * 4 + i;
                float part = v[i][0] * v[i][0] + v[i][1] * v[i][1]
                           + v[i][2] * v[i][2] + v[i][3] * v[i][3];
                part += __shfl_xor(part, 1, 64);
                part += __shfl_xor(part, 2, 64);
                part += __shfl_xor(part, 4, 64);
                part += __shfl_xor(part, 8, 64);   // 16-lane-group sum
                if (r16 == row) ss_own += part;    // defer cross-g reduce
                union { unsigned short s[4]; unsigned long long u; } pk;
#pragma unroll
                for (int j = 0; j < 4; ++j) pk.s[j] = f2bf(v[i][j]);
                const int byte = row * 512 + ((wr_slot ^ (row & 7)) << 4) + ((lane & 1) << 3);
                *reinterpret_cast<unsigned long long*>(wlds + byte) = pk.u;
            }
            if (ch < 3) { v[0] = nv[0]; v[1] = nv[1]; v[2] = nv[2]; v[3] = nv[3]; }
        }
        // ---- consume: kt = 8h .. 8h+7 (A from LDS, B from pnorm) ----------
#pragma unroll
        for (int kk = 0; kk < 8; ++kk) {
            const int slot = (g + kk * 4) ^ (r16 & 7);
            const short8 af = *reinterpret_cast<const short8*>(wlds + r16 * 512 + slot * 16);
            const int kt = h * 8 + kk;
            const unsigned short* bbase = pnorm + r16 * DIM + g * 8 + kt * 32;
#pragma unroll
            for (int c = 0; c < 4; ++c) {
                const short8 bf = *reinterpret_cast<const short8*>(bbase + c * 16 * DIM);
                acc[c] = __builtin_amdgcn_mfma_f32_16x16x32_bf16(af, bf, acc[c], 0, 0, 0);
            }
        }
    }

    // ---- finish |z|: cross-group reduce; redistribute to D-layout rows ----
    ss_own += __shfl_xor(ss_own, 16, 64);
    ss_own += __shfl_xor(ss_own, 32, 64);
    const float sc_own = TAU_INV / fmaxf(sqrtf(ss_own), 1e-12f);
    float sc[4];
#pragma unroll
    for (int q = 0; q < 4; ++q) sc[q] = __shfl(sc_own, g * 4 + q, 64);

    float lg[4][4];
#pragma unroll
    for (int c = 0; c < 4; ++c)
#pragma unroll
        for (int q = 0; q < 4; ++q) {
            lg[c][q] = acc[c][q] * sc[q];
            out_log[(n0 + g * 4 + q) * NPROTO + c * 16 + r16] = lg[c][q];
        }

    // ---- softmax over 64 protos per row -----------------------------------
    float w[4][4];
#pragma unroll
    for (int q = 0; q < 4; ++q) {
        float mx = fmaxf(fmaxf(lg[0][q], lg[1][q]), fmaxf(lg[2][q], lg[3][q]));
#pragma unroll
        for (int msk = 1; msk < 16; msk <<= 1) mx = fmaxf(mx, __shfl_xor(mx, msk, 64));
        const float e0 = __expf(lg[0][q] - mx);
        const float e1 = __expf(lg[1][q] - mx);
        const float e2 = __expf(lg[2][q] - mx);
        const float e3 = __expf(lg[3][q] - mx);
        float sum = e0 + e1 + e2 + e3;
#pragma unroll
        for (int msk = 1; msk < 16; msk <<= 1) sum += __shfl_xor(sum, msk, 64);
        const float inv = 1.0f / sum;
        w[0][q] = e0 * inv; w[1][q] = e1 * inv; w[2][q] = e2 * inv; w[3][q] = e3 * inv;
    }

    // ---- store w + wave-private LDS transpose (reuse wlds; in-order DS) ---
#pragma unroll
    for (int c = 0; c < 4; ++c)
#pragma unroll
        for (int q = 0; q < 4; ++q) {
            out_w[(n0 + g * 4 + q) * NPROTO + c * 16 + r16] = w[c][q];
            const int row  = g * 4 + q;
            const int col  = c * 16 + r16;
            const int byte = (row * 128 + col * 2) ^ ((row & 7) << 4);
            *reinterpret_cast<unsigned short*>(wlds + byte) = f2bf(w[c][q]);
        }

    short8 wa0, wa1;
    {
        const int b0 = (r16 * 128 + g * 16)      ^ ((r16 & 7) << 4);
        const int b1 = (r16 * 128 + g * 16 + 64) ^ ((r16 & 7) << 4);
        wa0 = *reinterpret_cast<const short8*>(wlds + b0);
        wa1 = *reinterpret_cast<const short8*>(wlds + b1);
    }

    // ---- pattern = w · protos : K=64, 32 col-tiles, 2-deep B prefetch -----
    short8 pbuf[2][2];
    const unsigned short* btile = protosT + r16 * NPROTO + g * 8;
    pbuf[0][0] = *reinterpret_cast<const short8*>(btile);
    pbuf[0][1] = *reinterpret_cast<const short8*>(btile + 32);
#pragma unroll
    for (int cp = 0; cp < 32; ++cp) {
        if (cp < 31) {
            const unsigned short* bn = btile + (cp + 1) * 16 * NPROTO;
            pbuf[(cp + 1) & 1][0] = *reinterpret_cast<const short8*>(bn);
            pbuf[(cp + 1) & 1][1] = *reinterpret_cast<const short8*>(bn + 32);
        }
        f32x4 p = {};
        p = __builtin_amdgcn_mfma_f32_16x16x32_bf16(wa0, pbuf[cp & 1][0], p, 0, 0, 0);
        p = __builtin_amdgcn_mfma_f32_16x16x32_bf16(wa1, pbuf[cp & 1][1], p, 0, 0, 0);
#pragma unroll
        for (int q = 0; q < 4; ++q)
            out_pat[(n0 + g * 4 + q) * DIM + cp * 16 + r16] = p[q];
    }
}

extern "C" void kernel_launch(void* const* d_in, const int* in_sizes, int n_in,
                              void* d_out, int out_size, void* d_ws, size_t ws_size,
                              hipStream_t stream) {
    const float* seg    = (const float*)d_in[0];
    const float* protos = (const float*)d_in[1];
    const int N = in_sizes[0] / DIM;  // 131072

    float* out     = (float*)d_out;
    float* out_pat = out;
    float* out_w   = out_pat + (size_t)N * DIM;
    float* out_log = out_w + (size_t)N * NPROTO;

    unsigned short* pnorm   = (unsigned short*)d_ws;
    unsigned short* protosT = pnorm + NPROTO * DIM;

    pb_prep<<<NPROTO, 64, 0, stream>>>(protos, pnorm, protosT);
    pb_main<<<N / 64, 256, 0, stream>>>(seg, pnorm, protosT, out_pat, out_w, out_log);
}

// Round 7
// 177.640 us; speedup vs baseline: 1.1304x; 1.1304x over previous
//
#include <hip/hip_runtime.h>
#include <hip/hip_bf16.h>

typedef __attribute__((ext_vector_type(8))) short short8;
typedef __attribute__((ext_vector_type(4))) float f32x4;

#define NPROTO 64
#define DIM    512
#define TAU_INV 5.0f

__device__ __forceinline__ unsigned short f2bf(float f) {
    union { float f; unsigned int u; } v; v.f = f;
    unsigned int r = v.u + 0x7FFFu + ((v.u >> 16) & 1u);  // round-to-nearest-even
    return (unsigned short)(r >> 16);
}

// ---------------------------------------------------------------------------
// Prep: p_norm (normalized protos, bf16, [64][512]) and protos^T (raw, bf16,
// [512][64]).
// ---------------------------------------------------------------------------
__global__ void pb_prep(const float* __restrict__ protos,
                        unsigned short* __restrict__ pnorm,
                        unsigned short* __restrict__ protosT) {
    const int k    = blockIdx.x;
    const int lane = threadIdx.x;
    const float* row = protos + k * DIM;
    float x[8];
    float ss = 0.0f;
#pragma unroll
    for (int j = 0; j < 8; ++j) {
        x[j] = row[lane * 8 + j];
        ss += x[j] * x[j];
    }
#pragma unroll
    for (int m = 1; m < 64; m <<= 1) ss += __shfl_xor(ss, m, 64);
    const float s = 1.0f / fmaxf(sqrtf(ss), 1e-12f);
    short8 pn;
#pragma unroll
    for (int j = 0; j < 8; ++j) pn[j] = (short)f2bf(x[j] * s);
    *reinterpret_cast<short8*>(pnorm + k * DIM + lane * 8) = pn;
#pragma unroll
    for (int j = 0; j < 8; ++j)
        protosT[(lane * 8 + j) * NPROTO + k] = f2bf(x[j]);
}

// ---------------------------------------------------------------------------
// Main v7: v2 structure (32 rows/wave, fused), ONE change: force the A-read
// pipeline to actually materialize in registers. launch_bounds(256,2)
// (allow up to 256 VGPR), 3-deep A-buffer ring (fully unrolled -> static
// indices), 2-deep B double-buffer. v2's shipped ISA had VGPR=64: the
// compiler had rematerialized the "prefetch" into load-before-use, so no
// read MLP ever existed. This is the single-lever test of that theory.
// ---------------------------------------------------------------------------
__global__ __launch_bounds__(256, 2) void pb_main(
    const float* __restrict__ seg,
    const unsigned short* __restrict__ pnorm,    // [64][512] bf16
    const unsigned short* __restrict__ protosT,  // [512][64] bf16
    float* __restrict__ out_pat,                 // [N][512]
    float* __restrict__ out_w,                   // [N][64]
    float* __restrict__ out_log) {               // [N][64]

    __shared__ unsigned short wbuf_all[4 * 2 * 16 * 64];  // 16KB

    const int wid  = (int)(threadIdx.x >> 6);
    const int lane = (int)(threadIdx.x & 63);
    const int g    = lane >> 4;
    const int r16  = lane & 15;
    const long n0  = ((long)blockIdx.x * 4 + wid) * 32;  // wave's first row

    // ---------------- logits matmul: K=512, 2 row-frags x 4 col-tiles --------
    f32x4 acc0[4] = {}, acc1[4] = {};
    float ss0 = 0.0f, ss1 = 0.0f;
    const float* ap0 = seg + (n0 + r16) * DIM + g * 8;
    const float* ap1 = ap0 + 16 * DIM;

    // A ring: [depth 3][a00,a01,a10,a11]; B: 2-deep
    f32x4 abuf[3][4];
    short8 bbuf[2][4];

#define ALOAD(SLOT, KT) do {                                                   \
    abuf[SLOT][0] = *reinterpret_cast<const f32x4*>(ap0 + (KT) * 32);          \
    abuf[SLOT][1] = *reinterpret_cast<const f32x4*>(ap0 + (KT) * 32 + 4);      \
    abuf[SLOT][2] = *reinterpret_cast<const f32x4*>(ap1 + (KT) * 32);          \
    abuf[SLOT][3] = *reinterpret_cast<const f32x4*>(ap1 + (KT) * 32 + 4);      \
} while (0)
#define BLOAD(SLOT, KT) do {                                                   \
    const unsigned short* _bb = pnorm + r16 * DIM + g * 8 + (KT) * 32;         \
    _Pragma("unroll")                                                          \
    for (int _c = 0; _c < 4; ++_c)                                             \
        bbuf[SLOT][_c] = *reinterpret_cast<const short8*>(_bb + _c * 16 * DIM);\
} while (0)

    ALOAD(0, 0); ALOAD(1, 1);
    BLOAD(0, 0);

#pragma unroll
    for (int kt = 0; kt < 16; ++kt) {
        const int cur = kt % 3;
        if (kt < 14) ALOAD((kt + 2) % 3, kt + 2);
        if (kt < 15) BLOAD((kt + 1) & 1, kt + 1);

        short8 af0, af1;
#pragma unroll
        for (int j = 0; j < 4; ++j) {
            const float x00 = abuf[cur][0][j], x01 = abuf[cur][1][j];
            const float x10 = abuf[cur][2][j], x11 = abuf[cur][3][j];
            ss0 += x00 * x00 + x01 * x01;
            ss1 += x10 * x10 + x11 * x11;
            af0[j] = (short)f2bf(x00); af0[j + 4] = (short)f2bf(x01);
            af1[j] = (short)f2bf(x10); af1[j + 4] = (short)f2bf(x11);
        }
#pragma unroll
        for (int c = 0; c < 4; ++c) {
            acc0[c] = __builtin_amdgcn_mfma_f32_16x16x32_bf16(af0, bbuf[kt & 1][c], acc0[c], 0, 0, 0);
            acc1[c] = __builtin_amdgcn_mfma_f32_16x16x32_bf16(af1, bbuf[kt & 1][c], acc1[c], 0, 0, 0);
        }
    }
#undef ALOAD
#undef BLOAD

    // ---- per-row 1/|z|, redistribute to D-layout rows ---------------------
    ss0 += __shfl_xor(ss0, 16, 64); ss0 += __shfl_xor(ss0, 32, 64);
    ss1 += __shfl_xor(ss1, 16, 64); ss1 += __shfl_xor(ss1, 32, 64);
    const float sco0 = TAU_INV / fmaxf(sqrtf(ss0), 1e-12f);
    const float sco1 = TAU_INV / fmaxf(sqrtf(ss1), 1e-12f);
    float sc0[4], sc1[4];
#pragma unroll
    for (int q = 0; q < 4; ++q) {
        sc0[q] = __shfl(sco0, g * 4 + q, 64);
        sc1[q] = __shfl(sco1, g * 4 + q, 64);
    }

    float lg0[4][4], lg1[4][4];
#pragma unroll
    for (int c = 0; c < 4; ++c)
#pragma unroll
        for (int q = 0; q < 4; ++q) {
            lg0[c][q] = acc0[c][q] * sc0[q];
            lg1[c][q] = acc1[c][q] * sc1[q];
            out_log[(n0 + g * 4 + q) * NPROTO + c * 16 + r16]      = lg0[c][q];
            out_log[(n0 + 16 + g * 4 + q) * NPROTO + c * 16 + r16] = lg1[c][q];
        }

    // ---- softmax over 64 protos per row -----------------------------------
    float w0[4][4], w1[4][4];
#pragma unroll
    for (int q = 0; q < 4; ++q) {
        float mx0 = fmaxf(fmaxf(lg0[0][q], lg0[1][q]), fmaxf(lg0[2][q], lg0[3][q]));
        float mx1 = fmaxf(fmaxf(lg1[0][q], lg1[1][q]), fmaxf(lg1[2][q], lg1[3][q]));
#pragma unroll
        for (int msk = 1; msk < 16; msk <<= 1) {
            mx0 = fmaxf(mx0, __shfl_xor(mx0, msk, 64));
            mx1 = fmaxf(mx1, __shfl_xor(mx1, msk, 64));
        }
        float e0[4], e1[4], sum0 = 0.0f, sum1 = 0.0f;
#pragma unroll
        for (int c = 0; c < 4; ++c) {
            e0[c] = __expf(lg0[c][q] - mx0); sum0 += e0[c];
            e1[c] = __expf(lg1[c][q] - mx1); sum1 += e1[c];
        }
#pragma unroll
        for (int msk = 1; msk < 16; msk <<= 1) {
            sum0 += __shfl_xor(sum0, msk, 64);
            sum1 += __shfl_xor(sum1, msk, 64);
        }
        const float i0 = 1.0f / sum0, i1 = 1.0f / sum1;
#pragma unroll
        for (int c = 0; c < 4; ++c) { w0[c][q] = e0[c] * i0; w1[c][q] = e1[c] * i1; }
    }

    // ---- store w + LDS transpose (D-layout -> A-layout), XOR swizzled -----
    unsigned short* wb0 = wbuf_all + (wid * 2 + 0) * 1024;
    unsigned short* wb1 = wbuf_all + (wid * 2 + 1) * 1024;
#pragma unroll
    for (int c = 0; c < 4; ++c)
#pragma unroll
        for (int q = 0; q < 4; ++q) {
            out_w[(n0 + g * 4 + q) * NPROTO + c * 16 + r16]      = w0[c][q];
            out_w[(n0 + 16 + g * 4 + q) * NPROTO + c * 16 + r16] = w1[c][q];
            const int row  = g * 4 + q;
            const int col  = c * 16 + r16;
            const int byte = (row * 128 + col * 2) ^ ((row & 7) << 4);
            *reinterpret_cast<unsigned short*>(reinterpret_cast<char*>(wb0) + byte) = f2bf(w0[c][q]);
            *reinterpret_cast<unsigned short*>(reinterpret_cast<char*>(wb1) + byte) = f2bf(w1[c][q]);
        }

    __syncthreads();

    short8 wa[2][2];
    {
        const int b0 = (r16 * 128 + g * 16)      ^ ((r16 & 7) << 4);
        const int b1 = (r16 * 128 + g * 16 + 64) ^ ((r16 & 7) << 4);
        wa[0][0] = *reinterpret_cast<const short8*>(reinterpret_cast<char*>(wb0) + b0);
        wa[0][1] = *reinterpret_cast<const short8*>(reinterpret_cast<char*>(wb0) + b1);
        wa[1][0] = *reinterpret_cast<const short8*>(reinterpret_cast<char*>(wb1) + b0);
        wa[1][1] = *reinterpret_cast<const short8*>(reinterpret_cast<char*>(wb1) + b1);
    }

    // ---- pattern = w · protos : K=64, 32 col-tiles, 2-deep B prefetch -----
    short8 pbuf[2][2];
    const unsigned short* btile = protosT + r16 * NPROTO + g * 8;
    pbuf[0][0] = *reinterpret_cast<const short8*>(btile);
    pbuf[0][1] = *reinterpret_cast<const short8*>(btile + 32);
#pragma unroll
    for (int cp = 0; cp < 32; ++cp) {
        if (cp < 31) {
            const unsigned short* bn = btile + (cp + 1) * 16 * NPROTO;
            pbuf[(cp + 1) & 1][0] = *reinterpret_cast<const short8*>(bn);
            pbuf[(cp + 1) & 1][1] = *reinterpret_cast<const short8*>(bn + 32);
        }
        f32x4 p0 = {}, p1 = {};
        p0 = __builtin_amdgcn_mfma_f32_16x16x32_bf16(wa[0][0], pbuf[cp & 1][0], p0, 0, 0, 0);
        p0 = __builtin_amdgcn_mfma_f32_16x16x32_bf16(wa[0][1], pbuf[cp & 1][1], p0, 0, 0, 0);
        p1 = __builtin_amdgcn_mfma_f32_16x16x32_bf16(wa[1][0], pbuf[cp & 1][0], p1, 0, 0, 0);
        p1 = __builtin_amdgcn_mfma_f32_16x16x32_bf16(wa[1][1], pbuf[cp & 1][1], p1, 0, 0, 0);
#pragma unroll
        for (int q = 0; q < 4; ++q) {
            out_pat[(n0 + g * 4 + q) * DIM + cp * 16 + r16]      = p0[q];
            out_pat[(n0 + 16 + g * 4 + q) * DIM + cp * 16 + r16] = p1[q];
        }
    }
}

extern "C" void kernel_launch(void* const* d_in, const int* in_sizes, int n_in,
                              void* d_out, int out_size, void* d_ws, size_t ws_size,
                              hipStream_t stream) {
    const float* seg    = (const float*)d_in[0];
    const float* protos = (const float*)d_in[1];
    const int N = in_sizes[0] / DIM;  // 131072

    float* out     = (float*)d_out;
    float* out_pat = out;
    float* out_w   = out_pat + (size_t)N * DIM;
    float* out_log = out_w + (size_t)N * NPROTO;

    unsigned short* pnorm   = (unsigned short*)d_ws;
    unsigned short* protosT = pnorm + NPROTO * DIM;

    pb_prep<<<NPROTO, 64, 0, stream>>>(protos, pnorm, protosT);
    pb_main<<<N / 128, 256, 0, stream>>>(seg, pnorm, protosT, out_pat, out_w, out_log);
}

// Round 8
// 171.086 us; speedup vs baseline: 1.1737x; 1.0383x over previous
//
#include <hip/hip_runtime.h>
#include <hip/hip_bf16.h>

typedef __attribute__((ext_vector_type(8))) short short8;
typedef __attribute__((ext_vector_type(4))) float f32x4;

#define NPROTO 64
#define DIM    512
#define TAU_INV 5.0f

#define AS1 __attribute__((address_space(1)))
#define AS3 __attribute__((address_space(3)))

__device__ __forceinline__ unsigned short f2bf(float f) {
    union { float f; unsigned int u; } v; v.f = f;
    unsigned int r = v.u + 0x7FFFu + ((v.u >> 16) & 1u);  // round-to-nearest-even
    return (unsigned short)(r >> 16);
}

// ---------------------------------------------------------------------------
// Prep:
//  pn2     [8 chunks][64 protos][64 cols bf16] -- normalized protos, chunk-major,
//          granule-XOR pre-swizzled (phys granule = logical ^ (proto&7)) so the
//          main kernel DMAs it linearly and ds_reads it conflict-free.
//  protosT [512][64] bf16 raw protos (epilogue B).
// ---------------------------------------------------------------------------
__global__ void pb_prep(const float* __restrict__ protos,
                        unsigned short* __restrict__ pn2,
                        unsigned short* __restrict__ protosT) {
    const int k    = blockIdx.x;
    const int lane = threadIdx.x;
    const float* row = protos + k * DIM;
    float x[8];
    float ss = 0.0f;
#pragma unroll
    for (int j = 0; j < 8; ++j) {
        x[j] = row[lane * 8 + j];
        ss += x[j] * x[j];
    }
#pragma unroll
    for (int m = 1; m < 64; m <<= 1) ss += __shfl_xor(ss, m, 64);
    const float s = 1.0f / fmaxf(sqrtf(ss), 1e-12f);
    short8 pn;
#pragma unroll
    for (int j = 0; j < 8; ++j) pn[j] = (short)f2bf(x[j] * s);
    // lane covers cols lane*8..+7 = chunk (lane>>3), logical granule (lane&7)
    const int chunk = lane >> 3;
    const int physg = (lane & 7) ^ (k & 7);
    *reinterpret_cast<short8*>(pn2 + chunk * 4096 + k * 64 + physg * 8) = pn;
#pragma unroll
    for (int j = 0; j < 8; ++j)
        protosT[(lane * 8 + j) * NPROTO + k] = f2bf(x[j]);
}

// ---------------------------------------------------------------------------
// Main v8: request-granularity fix on both read streams.
//  - A: global_load_lds, contiguous granule-permuted rows (8 x 128B segs/instr),
//       3-deep wave-private LDS pipe [3][wave][16 rows x 256B f32].
//  - B: global_load_lds linear copies of pn2 chunk slices (block-shared,
//       3-deep), ds_read_b128 conflict-free via baked XOR swizzle.
//  - counted vmcnt (never 0 mid-loop), raw s_barrier (no vmcnt(0) drain).
//  A-layout: row r (0..15), phys granule16B = logical ^ (r&15);
//            logical granule = float cols [4*lg .. 4*lg+3].
//  B-layout: proto p row 128B, phys granule = logical ^ (p&7);
//            logical granule = bf16 cols [8*lg .. 8*lg+7].
// ---------------------------------------------------------------------------
__global__ __launch_bounds__(256, 2) void pb_main(
    const float* __restrict__ seg,
    const unsigned short* __restrict__ pn2,      // [8][64][64] bf16 swizzled
    const unsigned short* __restrict__ protosT,  // [512][64] bf16
    float* __restrict__ out_pat,                 // [N][512]
    float* __restrict__ out_w,                   // [N][64]
    float* __restrict__ out_log) {               // [N][64]

    __shared__ char abuf[3][4][4096];            // 48KB A pipe (wave-private)
    __shared__ char bbuf[3][8192];               // 24KB B pipe (block-shared)
    __shared__ unsigned short wbuf_all[4 * 1024];// 8KB  w-transpose (wave-private)

    const int wid  = (int)(threadIdx.x >> 6);
    const int lane = (int)(threadIdx.x & 63);
    const int g    = lane >> 4;
    const int r16  = lane & 15;
    const long n0  = ((long)blockIdx.x * 4 + wid) * 16;  // wave's 16 rows

    // A-DMA source map: instr j covers rows 4j..4j+3.
    // dest byte i*16 -> row = 4j+(i>>4), phys granule = i&15,
    // source logical granule = (i&15) ^ (row&15).
    const float* srcA[4];
#pragma unroll
    for (int j = 0; j < 4; ++j) {
        const int row = j * 4 + (lane >> 4);
        const int lg  = (lane & 15) ^ (row & 15);
        srcA[j] = seg + (n0 + row) * DIM + lg * 4;
    }

#define STAGE(T) do {                                                          \
    char* _da = &abuf[(T) % 3][wid][0];                                        \
    _Pragma("unroll")                                                          \
    for (int _j = 0; _j < 4; ++_j)                                             \
        __builtin_amdgcn_global_load_lds(                                      \
            (const AS1 void*)(srcA[_j] + (T) * 64),                            \
            (AS3 void*)(_da + _j * 1024), 16, 0, 0);                           \
    char* _db = &bbuf[(T) % 3][wid * 2048];                                    \
    const unsigned short* _sb = pn2 + (T) * 4096 + wid * 1024 + lane * 8;      \
    _Pragma("unroll")                                                          \
    for (int _q = 0; _q < 2; ++_q)                                             \
        __builtin_amdgcn_global_load_lds(                                      \
            (const AS1 void*)(_sb + _q * 512),                                 \
            (AS3 void*)(_db + _q * 1024), 16, 0, 0);                           \
} while (0)

    f32x4 acc[4] = {};
    float ss = 0.0f;

    STAGE(0); STAGE(1); STAGE(2);   // 3 groups x 6 ops in flight

#pragma unroll
    for (int t = 0; t < 8; ++t) {
        // wait for group t (6 ops); keep later groups in flight
        if (t <= 5)      asm volatile("s_waitcnt vmcnt(12)" ::: "memory");
        else if (t == 6) asm volatile("s_waitcnt vmcnt(6)"  ::: "memory");
        else             asm volatile("s_waitcnt vmcnt(0)"  ::: "memory");
        __builtin_amdgcn_sched_barrier(0);
        __builtin_amdgcn_s_barrier();           // B slice t complete (all waves)
        __builtin_amdgcn_sched_barrier(0);

        const char* ab = &abuf[t % 3][wid][0];
        const char* bb = &bbuf[t % 3][0];
#pragma unroll
        for (int kk = 0; kk < 2; ++kk) {
            const int lga = (kk * 4 + g) * 2;
            const f32x4 a0 = *reinterpret_cast<const f32x4*>(
                ab + r16 * 256 + (((lga + 0) ^ r16) << 4));
            const f32x4 a1 = *reinterpret_cast<const f32x4*>(
                ab + r16 * 256 + (((lga + 1) ^ r16) << 4));
            short8 af;
#pragma unroll
            for (int j = 0; j < 4; ++j) {
                ss += a0[j] * a0[j] + a1[j] * a1[j];
                af[j]     = (short)f2bf(a0[j]);
                af[j + 4] = (short)f2bf(a1[j]);
            }
#pragma unroll
            for (int c = 0; c < 4; ++c) {
                const short8 bf = *reinterpret_cast<const short8*>(
                    bb + (c * 16 + r16) * 128 + (((kk * 4 + g) ^ (r16 & 7)) << 4));
                acc[c] = __builtin_amdgcn_mfma_f32_16x16x32_bf16(af, bf, acc[c], 0, 0, 0);
            }
        }
        asm volatile("s_waitcnt lgkmcnt(0)" ::: "memory");
        __builtin_amdgcn_sched_barrier(0);
        __builtin_amdgcn_s_barrier();           // all waves done reading slice t
        if (t <= 4) STAGE(t + 3);               // safe: buffer t%3 free
    }
#undef STAGE

    // ---- per-row 1/|z| (lane holds partial of row r16) --------------------
    ss += __shfl_xor(ss, 16, 64);
    ss += __shfl_xor(ss, 32, 64);
    const float sc_own = TAU_INV / fmaxf(sqrtf(ss), 1e-12f);
    float sc[4];
#pragma unroll
    for (int q = 0; q < 4; ++q) sc[q] = __shfl(sc_own, g * 4 + q, 64);

    float lg[4][4];
#pragma unroll
    for (int c = 0; c < 4; ++c)
#pragma unroll
        for (int q = 0; q < 4; ++q) {
            lg[c][q] = acc[c][q] * sc[q];
            out_log[(n0 + g * 4 + q) * NPROTO + c * 16 + r16] = lg[c][q];
        }

    // ---- softmax over 64 protos per row -----------------------------------
    float w[4][4];
#pragma unroll
    for (int q = 0; q < 4; ++q) {
        float mx = fmaxf(fmaxf(lg[0][q], lg[1][q]), fmaxf(lg[2][q], lg[3][q]));
#pragma unroll
        for (int msk = 1; msk < 16; msk <<= 1) mx = fmaxf(mx, __shfl_xor(mx, msk, 64));
        const float e0 = __expf(lg[0][q] - mx);
        const float e1 = __expf(lg[1][q] - mx);
        const float e2 = __expf(lg[2][q] - mx);
        const float e3 = __expf(lg[3][q] - mx);
        float sum = e0 + e1 + e2 + e3;
#pragma unroll
        for (int msk = 1; msk < 16; msk <<= 1) sum += __shfl_xor(sum, msk, 64);
        const float inv = 1.0f / sum;
        w[0][q] = e0 * inv; w[1][q] = e1 * inv; w[2][q] = e2 * inv; w[3][q] = e3 * inv;
    }

    // ---- store w + wave-private LDS transpose (XOR swizzled) --------------
    char* wb = reinterpret_cast<char*>(wbuf_all + wid * 1024);
#pragma unroll
    for (int c = 0; c < 4; ++c)
#pragma unroll
        for (int q = 0; q < 4; ++q) {
            out_w[(n0 + g * 4 + q) * NPROTO + c * 16 + r16] = w[c][q];
            const int row  = g * 4 + q;
            const int col  = c * 16 + r16;
            const int byte = (row * 128 + col * 2) ^ ((row & 7) << 4);
            *reinterpret_cast<unsigned short*>(wb + byte) = f2bf(w[c][q]);
        }

    short8 wa0, wa1;
    {
        const int b0 = (r16 * 128 + g * 16)      ^ ((r16 & 7) << 4);
        const int b1 = (r16 * 128 + g * 16 + 64) ^ ((r16 & 7) << 4);
        wa0 = *reinterpret_cast<const short8*>(wb + b0);
        wa1 = *reinterpret_cast<const short8*>(wb + b1);
    }

    // ---- pattern = w · protos : K=64, 32 col-tiles, 2-deep B prefetch -----
    short8 pbuf[2][2];
    const unsigned short* btile = protosT + r16 * NPROTO + g * 8;
    pbuf[0][0] = *reinterpret_cast<const short8*>(btile);
    pbuf[0][1] = *reinterpret_cast<const short8*>(btile + 32);
#pragma unroll
    for (int cp = 0; cp < 32; ++cp) {
        if (cp < 31) {
            const unsigned short* bn = btile + (cp + 1) * 16 * NPROTO;
            pbuf[(cp + 1) & 1][0] = *reinterpret_cast<const short8*>(bn);
            pbuf[(cp + 1) & 1][1] = *reinterpret_cast<const short8*>(bn + 32);
        }
        f32x4 p = {};
        p = __builtin_amdgcn_mfma_f32_16x16x32_bf16(wa0, pbuf[cp & 1][0], p, 0, 0, 0);
        p = __builtin_amdgcn_mfma_f32_16x16x32_bf16(wa1, pbuf[cp & 1][1], p, 0, 0, 0);
#pragma unroll
        for (int q = 0; q < 4; ++q)
            out_pat[(n0 + g * 4 + q) * DIM + cp * 16 + r16] = p[q];
    }
}

extern "C" void kernel_launch(void* const* d_in, const int* in_sizes, int n_in,
                              void* d_out, int out_size, void* d_ws, size_t ws_size,
                              hipStream_t stream) {
    const float* seg    = (const float*)d_in[0];
    const float* protos = (const float*)d_in[1];
    const int N = in_sizes[0] / DIM;  // 131072

    float* out     = (float*)d_out;
    float* out_pat = out;
    float* out_w   = out_pat + (size_t)N * DIM;
    float* out_log = out_w + (size_t)N * NPROTO;

    unsigned short* pn2     = (unsigned short*)d_ws;        // 64KB
    unsigned short* protosT = pn2 + 8 * 64 * 64;            // 64KB

    pb_prep<<<NPROTO, 64, 0, stream>>>(protos, pn2, protosT);
    pb_main<<<N / 64, 256, 0, stream>>>(seg, pn2, protosT, out_pat, out_w, out_log);
}